// Round 1
// baseline (573.732 us; speedup 1.0000x reference)
//
#include <hip/hip_runtime.h>
#include <hip/hip_bf16.h>
#include <stdint.h>

#define N_NODES   100000
#define N_EDGES   3200000
#define IN_FEAT   128
#define OUT_FEAT  128
#define NUM_RELS  16
#define NUM_BASES 8
#define M_PAD     100096      // 782 * 128
#define NBKT      391         // coarse buckets per chunk = ceil(100000/256)
#define NB        256         // blocks in coarse hist/place (must match both)

using short8 = __attribute__((ext_vector_type(8))) short;
using v4f    = __attribute__((ext_vector_type(4))) float;

__device__ inline unsigned short f2bf_rne(float f) {
    __hip_bfloat16 h = __float2bfloat16(f);
    return *reinterpret_cast<unsigned short*>(&h);
}
__device__ inline float bf2f(unsigned short u) {
    union { uint32_t i; float f; } x;
    x.i = ((uint32_t)u) << 16;
    return x.f;
}

// ---------------------------------------------------------------------------
// x fp32 -> bf16, zero-padded to M_PAD rows
// ---------------------------------------------------------------------------
__global__ void conv_x(const float* __restrict__ x, unsigned short* __restrict__ xb) {
    int id = blockIdx.x * 256 + threadIdx.x;
    int base = id * 4;
    ushort4 o;
    if (base < N_NODES * IN_FEAT) {
        const float4 v = reinterpret_cast<const float4*>(x)[id];
        o.x = f2bf_rne(v.x); o.y = f2bf_rne(v.y);
        o.z = f2bf_rne(v.z); o.w = f2bf_rne(v.w);
    } else {
        o.x = o.y = o.z = o.w = 0;
    }
    reinterpret_cast<ushort4*>(xb)[id] = o;
}

// ---------------------------------------------------------------------------
// Bt[n][k] = sum_b w_comp[r][b] * weight[b][k][o], n = r*128+o (bf16)
// ---------------------------------------------------------------------------
__global__ void build_w(const float* __restrict__ weight,
                        const float* __restrict__ w_comp,
                        unsigned short* __restrict__ Bt) {
    int id = blockIdx.x * 256 + threadIdx.x;
    int n = id >> 7;
    int k = id & 127;
    int r = n >> 7;
    int o = n & 127;
    float acc = 0.f;
#pragma unroll
    for (int b = 0; b < NUM_BASES; ++b)
        acc += w_comp[r * NUM_BASES + b] * weight[(b * IN_FEAT + k) * OUT_FEAT + o];
    Bt[id] = f2bf_rne(acc);
}

// ---------------------------------------------------------------------------
// Two-level sort by (chunk, dst). Coarse bucket b = chunk*NBKT + (dst>>8).
// Phase 1: per-block LDS histogram -> histG[b*NB + nb]  (no global atomics)
// ---------------------------------------------------------------------------
__global__ __launch_bounds__(1024) void coarse_hist(const int* __restrict__ dst,
                                                    const int* __restrict__ et,
                                                    int* __restrict__ histG,
                                                    int lg, int nbuck) {
    extern __shared__ int lh[];
    for (int i = threadIdx.x; i < nbuck; i += 1024) lh[i] = 0;
    __syncthreads();
    const int stride = NB * 1024;
    for (int e = blockIdx.x * 1024 + threadIdx.x; e < N_EDGES; e += stride)
        atomicAdd(&lh[(et[e] >> lg) * NBKT + (dst[e] >> 8)], 1);
    __syncthreads();
    for (int i = threadIdx.x; i < nbuck; i += 1024)
        histG[i * NB + blockIdx.x] = lh[i];
}

// ---------------------------------------------------------------------------
// 2-level in-place exclusive scan of data[0..K): part -> mid -> final
// ---------------------------------------------------------------------------
__global__ void scan_part(const int* __restrict__ data, int* __restrict__ partial, int K) {
    __shared__ int sh[256];
    const int tid = threadIdx.x, b = blockIdx.x;
    const int i0 = b * 4096 + tid * 16;
    int s = 0;
#pragma unroll
    for (int k = 0; k < 16; ++k) { int i = i0 + k; if (i < K) s += data[i]; }
    sh[tid] = s;
    __syncthreads();
    for (int st = 128; st > 0; st >>= 1) {
        if (tid < st) sh[tid] += sh[tid + st];
        __syncthreads();
    }
    if (tid == 0) partial[b] = sh[0];
}

__global__ __launch_bounds__(512) void scan_mid(int* __restrict__ partial, int G) {
    __shared__ int sh[512];
    const int tid = threadIdx.x;
    int v = (tid < G) ? partial[tid] : 0;
    sh[tid] = v;
    __syncthreads();
    for (int st = 1; st < 512; st <<= 1) {
        int t = (tid >= st) ? sh[tid - st] : 0;
        __syncthreads();
        sh[tid] += t;
        __syncthreads();
    }
    if (tid < G) partial[tid] = sh[tid] - v;        // exclusive
}

// in-place: each element read before overwrite by the same thread
__global__ void scan_final(int* __restrict__ data, const int* __restrict__ partial, int K) {
    __shared__ int sh[256];
    const int tid = threadIdx.x, b = blockIdx.x;
    const int i0 = b * 4096 + tid * 16;
    int s = 0;
#pragma unroll
    for (int k = 0; k < 16; ++k) { int i = i0 + k; if (i < K) s += data[i]; }
    sh[tid] = s;
    __syncthreads();
    for (int st = 1; st < 256; st <<= 1) {
        int t = (tid >= st) ? sh[tid - st] : 0;
        __syncthreads();
        sh[tid] += t;
        __syncthreads();
    }
    int run = partial[b] + sh[tid] - s;
#pragma unroll
    for (int k = 0; k < 16; ++k) {
        int i = i0 + k;
        if (i < K) {
            int c = data[i];
            data[i] = run;
            run += c;
        }
    }
}

// ---------------------------------------------------------------------------
// Phase 2: place edges into bucket-contiguous regions using exact reserved
// ranges (histS = scanned histG). LDS cursors only; writes are ~16-entry runs.
// entry = (dst&255)<<21 | src<<4 | rl   (29 bits)
// ---------------------------------------------------------------------------
__global__ __launch_bounds__(1024) void coarse_place(const int* __restrict__ src,
                                                     const int* __restrict__ dst,
                                                     const int* __restrict__ et,
                                                     const int* __restrict__ histS,
                                                     int* __restrict__ entries,
                                                     int lg, int RCm1, int nbuck) {
    extern __shared__ int cur[];
    for (int i = threadIdx.x; i < nbuck; i += 1024)
        cur[i] = histS[i * NB + blockIdx.x];
    __syncthreads();
    const int stride = NB * 1024;
    for (int e = blockIdx.x * 1024 + threadIdx.x; e < N_EDGES; e += stride) {
        int t = et[e], d = dst[e];
        int b = (t >> lg) * NBKT + (d >> 8);
        int pos = atomicAdd(&cur[b], 1);
        entries[pos] = ((d & 255) << 21) | (src[e] << 4) | (t & RCm1);
    }
}

// ---------------------------------------------------------------------------
// Phase 3: one block per bucket; counting sort by dst-low-8 in LDS (2-pass,
// no capacity limit). Emits coalesced perm runs AND per-node off[] directly.
// ---------------------------------------------------------------------------
__global__ __launch_bounds__(256) void fine_sort(const int* __restrict__ entries,
                                                 const int* __restrict__ histS,
                                                 int* __restrict__ perm,
                                                 int* __restrict__ off,
                                                 int nbuck, int nch) {
    __shared__ int cnt[256];
    __shared__ int bs[256];
    const int tid = threadIdx.x, b = blockIdx.x;
    const int start = histS[b * NB];
    const int end   = (b + 1 < nbuck) ? histS[(b + 1) * NB] : N_EDGES;

    cnt[tid] = 0;
    __syncthreads();
    for (int i = start + tid; i < end; i += 256)
        atomicAdd(&cnt[entries[i] >> 21], 1);
    __syncthreads();

    int v = cnt[tid];
    bs[tid] = v;
    __syncthreads();
    for (int st = 1; st < 256; st <<= 1) {
        int t = (tid >= st) ? bs[tid - st] : 0;
        __syncthreads();
        bs[tid] += t;
        __syncthreads();
    }
    const int excl = bs[tid] - v;      // exclusive prefix among dlow

    const int c  = b / NBKT;
    const int dh = b % NBKT;
    const int d  = dh * 256 + tid;
    if (d < N_NODES) off[c * N_NODES + d] = start + excl;
    if (b == nbuck - 1 && tid == 0) off[nch * N_NODES] = N_EDGES;

    __syncthreads();
    cnt[tid] = excl;                   // cursor
    __syncthreads();
    for (int i = start + tid; i < end; i += 256) {
        int en = entries[i];
        int p = atomicAdd(&cnt[en >> 21], 1);
        perm[start + p] = en & 0x1FFFFF;   // (src<<4)|rl
    }
}

// ---------------------------------------------------------------------------
// GEMM, m97-style: 128x128 tile, K=128 via global_load_lds(16B), XOR-swizzled
// ---------------------------------------------------------------------------
__global__ __launch_bounds__(256, 2) void gemm_h(const unsigned short* __restrict__ xb,
                                                 const unsigned short* __restrict__ Bt,
                                                 unsigned short* __restrict__ h2,
                                                 int c, int RC) {
    __shared__ unsigned short lA[128 * 128];
    __shared__ unsigned short lB[128 * 128];

    const int mb = blockIdx.x;
    const int rl = blockIdx.y;
    const int r  = c * RC + rl;
    const int tid  = threadIdx.x;
    const int wid  = tid >> 6;
    const int lane = tid & 63;

    const unsigned short* gA = xb + (size_t)mb * 128 * IN_FEAT;
    const unsigned short* gB = Bt + (size_t)r  * 128 * IN_FEAT;

#pragma unroll
    for (int it = 0; it < 8; ++it) {
        int sbase = it * 256 + wid * 64;
        int s = sbase + lane;
        int row = s >> 4;
        int cc = (s & 15) ^ (row & 15);
        __builtin_amdgcn_global_load_lds(
            (const __attribute__((address_space(1))) void*)(gA + row * 128 + cc * 8),
            (__attribute__((address_space(3))) void*)(&lA[sbase * 8]), 16, 0, 0);
    }
#pragma unroll
    for (int it = 0; it < 8; ++it) {
        int sbase = it * 256 + wid * 64;
        int s = sbase + lane;
        int row = s >> 4;
        int cc = (s & 15) ^ (row & 15);
        __builtin_amdgcn_global_load_lds(
            (const __attribute__((address_space(1))) void*)(gB + row * 128 + cc * 8),
            (__attribute__((address_space(3))) void*)(&lB[sbase * 8]), 16, 0, 0);
    }
    __syncthreads();

    const int wm = wid >> 1, wn = wid & 1;
    const int ml = lane & 15, kgrp = lane >> 4;

    v4f acc[4][4];
#pragma unroll
    for (int i = 0; i < 4; ++i)
#pragma unroll
        for (int j = 0; j < 4; ++j)
            acc[i][j] = (v4f){0.f, 0.f, 0.f, 0.f};

#pragma unroll
    for (int kb = 0; kb < 4; ++kb) {
        const int cc = kb * 4 + kgrp;
        short8 af[4], bfr[4];
#pragma unroll
        for (int tm = 0; tm < 4; ++tm) {
            int rA = wm * 64 + tm * 16 + ml;
            af[tm] = *reinterpret_cast<const short8*>(&lA[(rA * 16 + (cc ^ (rA & 15))) * 8]);
        }
#pragma unroll
        for (int tn = 0; tn < 4; ++tn) {
            int rB = wn * 64 + tn * 16 + ml;
            bfr[tn] = *reinterpret_cast<const short8*>(&lB[(rB * 16 + (cc ^ (rB & 15))) * 8]);
        }
#pragma unroll
        for (int tm = 0; tm < 4; ++tm)
#pragma unroll
            for (int tn = 0; tn < 4; ++tn)
                acc[tm][tn] = __builtin_amdgcn_mfma_f32_16x16x32_bf16(af[tm], bfr[tn], acc[tm][tn], 0, 0, 0);
    }

    const int ncols = RC * 128;
    const int row0 = mb * 128 + wm * 64;
    const int col0 = rl * 128 + wn * 64;
#pragma unroll
    for (int tm = 0; tm < 4; ++tm)
#pragma unroll
        for (int rr = 0; rr < 4; ++rr) {
            int row = row0 + tm * 16 + kgrp * 4 + rr;
            size_t rb = (size_t)row * ncols;
#pragma unroll
            for (int tn = 0; tn < 4; ++tn) {
                int col = col0 + tn * 16 + ml;
                h2[rb + col] = f2bf_rne(acc[tm][tn][rr]);
            }
        }
}

// ---------------------------------------------------------------------------
// Gather: one wave per (chunk, node) segment; unroll x8 for MLP. RC is a
// template param so the h2 row stride is a compile-time shift (no v_mul in
// the address chain).
// ---------------------------------------------------------------------------
template <int RCT>
__global__ void gatherT(const int* __restrict__ off, const int* __restrict__ perm,
                        const unsigned short* __restrict__ h2,
                        const float* __restrict__ bias,
                        float* __restrict__ out, int c) {
    const int d = blockIdx.x * 4 + (threadIdx.x >> 6);
    const int lane = threadIdx.x & 63;
    const int kb = c * N_NODES + d;
    const int e0 = off[kb], e1 = off[kb + 1];
    const unsigned short* hb = h2 + lane * 2;   // lane-fixed byte offset
    float2 acc = make_float2(0.f, 0.f);
    int e = e0;
    for (; e + 8 <= e1; e += 8) {
        int p[8];
#pragma unroll
        for (int j = 0; j < 8; ++j) p[j] = perm[e + j];
        ushort2 v[8];
#pragma unroll
        for (int j = 0; j < 8; ++j)
            v[j] = *reinterpret_cast<const ushort2*>(
                hb + ((size_t)(p[j] >> 4) * RCT + (p[j] & 15)) * 128);
#pragma unroll
        for (int j = 0; j < 8; ++j) {
            acc.x += bf2f(v[j].x);
            acc.y += bf2f(v[j].y);
        }
    }
    for (; e + 2 <= e1; e += 2) {
        int p0 = perm[e], p1 = perm[e + 1];
        ushort2 v0 = *reinterpret_cast<const ushort2*>(
            hb + ((size_t)(p0 >> 4) * RCT + (p0 & 15)) * 128);
        ushort2 v1 = *reinterpret_cast<const ushort2*>(
            hb + ((size_t)(p1 >> 4) * RCT + (p1 & 15)) * 128);
        acc.x += bf2f(v0.x) + bf2f(v1.x);
        acc.y += bf2f(v0.y) + bf2f(v1.y);
    }
    for (; e < e1; ++e) {
        int p = perm[e];
        ushort2 v = *reinterpret_cast<const ushort2*>(
            hb + ((size_t)(p >> 4) * RCT + (p & 15)) * 128);
        acc.x += bf2f(v.x);
        acc.y += bf2f(v.y);
    }
    float* po = out + (size_t)d * OUT_FEAT + lane * 2;
    if (c == 0) {
        acc.x += bias[lane * 2];
        acc.y += bias[lane * 2 + 1];
    } else {
        float2 prev = *reinterpret_cast<const float2*>(po);
        acc.x += prev.x;
        acc.y += prev.y;
    }
    *reinterpret_cast<float2*>(po) = acc;
}

static inline size_t align256(size_t a) { return (a + 255) & ~(size_t)255; }

extern "C" void kernel_launch(void* const* d_in, const int* in_sizes, int n_in,
                              void* d_out, int out_size, void* d_ws, size_t ws_size,
                              hipStream_t stream) {
    const float* x      = (const float*)d_in[0];
    const float* weight = (const float*)d_in[1];
    const float* w_comp = (const float*)d_in[2];
    const float* h_bias = (const float*)d_in[3];
    const int*   src    = (const int*)d_in[4];
    const int*   dst    = (const int*)d_in[5];
    const int*   etypes = (const int*)d_in[6];
    float* out = (float*)d_out;

    const size_t per_rel = (size_t)M_PAD * 128 * 2;   // 25,624,576 B

    // RC = relations per chunk. Force RC=4 so the reused h2 buffer is
    // 4*25.6 = 102 MB: together with xb (25.6), out (51) and perm (13) the
    // gather-phase working set (~190 MB) fits the 256 MB Infinity Cache.
    // h2 is rewritten in place every chunk, so its HBM writeback is only
    // capacity-eviction-driven instead of the full 410 MB stream, and the
    // gather's scattered 256 B reads become L3 hits. (RC=8 -> 205 MB h2
    // alone is too tight; RC=2 -> 8 out-accumulation passes cost more than
    // they save.) Fallback loop retained for small workspaces.
    int RC = 4, lg = 2;
    size_t perm_o = 0, off_o = 0, part_o = 0, h2_o = 0;
    for (;;) {
        int nch = NUM_RELS / RC;
        size_t a = 512 * 1024;                                   // Bt
        a = align256(a + per_rel);                               // xb
        perm_o = a; a = align256(a + (size_t)N_EDGES * 4);       // perm
        off_o  = a; a = align256(a + ((size_t)nch * N_NODES + 1) * 4);
        part_o = a; a = align256(a + 512 * 4);                   // scan partials
        h2_o   = a; a += per_rel * (size_t)RC;                   // h2 (>= 25.6MB)
        if (a <= ws_size || RC == 1) break;
        RC >>= 1; lg -= 1;
    }
    const int nch = NUM_RELS / RC;
    const int nbuck = nch * NBKT;
    const int K2 = nbuck * NB;
    const int G2 = (K2 + 4095) / 4096;

    char* w = (char*)d_ws;
    unsigned short* Bt      = (unsigned short*)(w);
    unsigned short* xb      = (unsigned short*)(w + 512 * 1024);
    int*            perm    = (int*)(w + perm_o);
    int*            off     = (int*)(w + off_o);
    int*            partial = (int*)(w + part_o);
    unsigned short* h2      = (unsigned short*)(w + h2_o);
    int*            entries = (int*)(w + h2_o);                  // alias h2[0..12.8MB)
    int*            histG   = (int*)(w + h2_o + 13 * 1024 * 1024); // alias h2[13MB..)

    conv_x<<<12512, 256, 0, stream>>>(x, xb);
    build_w<<<1024, 256, 0, stream>>>(weight, w_comp, Bt);

    coarse_hist<<<NB, 1024, nbuck * 4, stream>>>(dst, etypes, histG, lg, nbuck);
    scan_part<<<G2, 256, 0, stream>>>(histG, partial, K2);
    scan_mid<<<1, 512, 0, stream>>>(partial, G2);
    scan_final<<<G2, 256, 0, stream>>>(histG, partial, K2);
    coarse_place<<<NB, 1024, nbuck * 4, stream>>>(src, dst, etypes, histG, entries,
                                                  lg, RC - 1, nbuck);
    fine_sort<<<nbuck, 256, 0, stream>>>(entries, histG, perm, off, nbuck, nch);

    for (int c = 0; c < nch; ++c) {
        gemm_h<<<dim3(782, RC), 256, 0, stream>>>(xb, Bt, h2, c, RC);
        switch (RC) {
            case 16: gatherT<16><<<25000, 256, 0, stream>>>(off, perm, h2, h_bias, out, c); break;
            case 8:  gatherT<8> <<<25000, 256, 0, stream>>>(off, perm, h2, h_bias, out, c); break;
            case 4:  gatherT<4> <<<25000, 256, 0, stream>>>(off, perm, h2, h_bias, out, c); break;
            case 2:  gatherT<2> <<<25000, 256, 0, stream>>>(off, perm, h2, h_bias, out, c); break;
            default: gatherT<1> <<<25000, 256, 0, stream>>>(off, perm, h2, h_bias, out, c); break;
        }
    }
}

// Round 2
// 540.715 us; speedup vs baseline: 1.0611x; 1.0611x over previous
//
#include <hip/hip_runtime.h>
#include <hip/hip_bf16.h>
#include <stdint.h>

#define N_NODES   100000
#define N_EDGES   3200000
#define IN_FEAT   128
#define OUT_FEAT  128
#define NUM_RELS  16
#define NUM_BASES 8
#define M_PAD     100096      // 782 * 128
#define NBKT      391         // coarse buckets per chunk = ceil(100000/256)
#define NB        512         // blocks in coarse hist/place (must match both)

using short8 = __attribute__((ext_vector_type(8))) short;
using v4f    = __attribute__((ext_vector_type(4))) float;

__device__ inline unsigned short f2bf_rne(float f) {
    __hip_bfloat16 h = __float2bfloat16(f);
    return *reinterpret_cast<unsigned short*>(&h);
}
__device__ inline float bf2f(unsigned short u) {
    union { uint32_t i; float f; } x;
    x.i = ((uint32_t)u) << 16;
    return x.f;
}

// ---------------------------------------------------------------------------
// x fp32 -> bf16, zero-padded to M_PAD rows
// ---------------------------------------------------------------------------
__global__ void conv_x(const float* __restrict__ x, unsigned short* __restrict__ xb) {
    int id = blockIdx.x * 256 + threadIdx.x;
    int base = id * 4;
    ushort4 o;
    if (base < N_NODES * IN_FEAT) {
        const float4 v = reinterpret_cast<const float4*>(x)[id];
        o.x = f2bf_rne(v.x); o.y = f2bf_rne(v.y);
        o.z = f2bf_rne(v.z); o.w = f2bf_rne(v.w);
    } else {
        o.x = o.y = o.z = o.w = 0;
    }
    reinterpret_cast<ushort4*>(xb)[id] = o;
}

// ---------------------------------------------------------------------------
// Bt[n][k] = sum_b w_comp[r][b] * weight[b][k][o], n = r*128+o (bf16)
// ---------------------------------------------------------------------------
__global__ void build_w(const float* __restrict__ weight,
                        const float* __restrict__ w_comp,
                        unsigned short* __restrict__ Bt) {
    int id = blockIdx.x * 256 + threadIdx.x;
    int n = id >> 7;
    int k = id & 127;
    int r = n >> 7;
    int o = n & 127;
    float acc = 0.f;
#pragma unroll
    for (int b = 0; b < NUM_BASES; ++b)
        acc += w_comp[r * NUM_BASES + b] * weight[(b * IN_FEAT + k) * OUT_FEAT + o];
    Bt[id] = f2bf_rne(acc);
}

// ---------------------------------------------------------------------------
// Two-level sort by (chunk, dst). Coarse bucket b = chunk*NBKT + (dst>>8).
// Phase 1: per-block LDS histogram -> histG[b*NB + nb]  (no global atomics)
// 4 edges per iteration via int4 loads: 2x fewer dependent chains, 16B loads.
// ---------------------------------------------------------------------------
__global__ __launch_bounds__(512) void coarse_hist(const int* __restrict__ dst,
                                                   const int* __restrict__ et,
                                                   int* __restrict__ histG,
                                                   int lg, int nbuck) {
    extern __shared__ int lh[];
    for (int i = threadIdx.x; i < nbuck; i += 512) lh[i] = 0;
    __syncthreads();
    const int NG = N_EDGES / 4;
    const int stride = NB * 512;
    for (int g = blockIdx.x * 512 + threadIdx.x; g < NG; g += stride) {
        const int4 d4 = reinterpret_cast<const int4*>(dst)[g];
        const int4 t4 = reinterpret_cast<const int4*>(et)[g];
        atomicAdd(&lh[(t4.x >> lg) * NBKT + (d4.x >> 8)], 1);
        atomicAdd(&lh[(t4.y >> lg) * NBKT + (d4.y >> 8)], 1);
        atomicAdd(&lh[(t4.z >> lg) * NBKT + (d4.z >> 8)], 1);
        atomicAdd(&lh[(t4.w >> lg) * NBKT + (d4.w >> 8)], 1);
    }
    __syncthreads();
    for (int i = threadIdx.x; i < nbuck; i += 512)
        histG[i * NB + blockIdx.x] = lh[i];
}

// ---------------------------------------------------------------------------
// 2-level in-place exclusive scan of data[0..K): part -> mid -> final
// ---------------------------------------------------------------------------
__global__ void scan_part(const int* __restrict__ data, int* __restrict__ partial, int K) {
    __shared__ int sh[256];
    const int tid = threadIdx.x, b = blockIdx.x;
    const int i0 = b * 4096 + tid * 16;
    int s = 0;
#pragma unroll
    for (int k = 0; k < 16; ++k) { int i = i0 + k; if (i < K) s += data[i]; }
    sh[tid] = s;
    __syncthreads();
    for (int st = 128; st > 0; st >>= 1) {
        if (tid < st) sh[tid] += sh[tid + st];
        __syncthreads();
    }
    if (tid == 0) partial[b] = sh[0];
}

__global__ __launch_bounds__(512) void scan_mid(int* __restrict__ partial, int G) {
    __shared__ int sh[512];
    const int tid = threadIdx.x;
    int v = (tid < G) ? partial[tid] : 0;
    sh[tid] = v;
    __syncthreads();
    for (int st = 1; st < 512; st <<= 1) {
        int t = (tid >= st) ? sh[tid - st] : 0;
        __syncthreads();
        sh[tid] += t;
        __syncthreads();
    }
    if (tid < G) partial[tid] = sh[tid] - v;        // exclusive
}

// in-place: each element read before overwrite by the same thread
__global__ void scan_final(int* __restrict__ data, const int* __restrict__ partial, int K) {
    __shared__ int sh[256];
    const int tid = threadIdx.x, b = blockIdx.x;
    const int i0 = b * 4096 + tid * 16;
    int s = 0;
#pragma unroll
    for (int k = 0; k < 16; ++k) { int i = i0 + k; if (i < K) s += data[i]; }
    sh[tid] = s;
    __syncthreads();
    for (int st = 1; st < 256; st <<= 1) {
        int t = (tid >= st) ? sh[tid - st] : 0;
        __syncthreads();
        sh[tid] += t;
        __syncthreads();
    }
    int run = partial[b] + sh[tid] - s;
#pragma unroll
    for (int k = 0; k < 16; ++k) {
        int i = i0 + k;
        if (i < K) {
            int c = data[i];
            data[i] = run;
            run += c;
        }
    }
}

// ---------------------------------------------------------------------------
// Phase 2: place edges into bucket-contiguous regions using exact reserved
// ranges (histS = scanned histG). LDS cursors only.
// 4 edges/iter: int4 loads, 4 independent atomic->store chains in flight.
// With NB=512 the average (block,bucket) run is 16 entries = one 64B line,
// so the scattered stores write-combine to full lines.
// entry = (dst&255)<<21 | src<<4 | rl   (29 bits)
// ---------------------------------------------------------------------------
__global__ __launch_bounds__(512) void coarse_place(const int* __restrict__ src,
                                                    const int* __restrict__ dst,
                                                    const int* __restrict__ et,
                                                    const int* __restrict__ histS,
                                                    int* __restrict__ entries,
                                                    int lg, int RCm1, int nbuck) {
    extern __shared__ int cur[];
    for (int i = threadIdx.x; i < nbuck; i += 512)
        cur[i] = histS[i * NB + blockIdx.x];
    __syncthreads();
    const int NG = N_EDGES / 4;
    const int stride = NB * 512;
    for (int g = blockIdx.x * 512 + threadIdx.x; g < NG; g += stride) {
        const int4 s4 = reinterpret_cast<const int4*>(src)[g];
        const int4 d4 = reinterpret_cast<const int4*>(dst)[g];
        const int4 t4 = reinterpret_cast<const int4*>(et)[g];
        int b0 = (t4.x >> lg) * NBKT + (d4.x >> 8);
        int b1 = (t4.y >> lg) * NBKT + (d4.y >> 8);
        int b2 = (t4.z >> lg) * NBKT + (d4.z >> 8);
        int b3 = (t4.w >> lg) * NBKT + (d4.w >> 8);
        int p0 = atomicAdd(&cur[b0], 1);
        int p1 = atomicAdd(&cur[b1], 1);
        int p2 = atomicAdd(&cur[b2], 1);
        int p3 = atomicAdd(&cur[b3], 1);
        entries[p0] = ((d4.x & 255) << 21) | (s4.x << 4) | (t4.x & RCm1);
        entries[p1] = ((d4.y & 255) << 21) | (s4.y << 4) | (t4.y & RCm1);
        entries[p2] = ((d4.z & 255) << 21) | (s4.z << 4) | (t4.z & RCm1);
        entries[p3] = ((d4.w & 255) << 21) | (s4.w << 4) | (t4.w & RCm1);
    }
}

// ---------------------------------------------------------------------------
// Phase 3: one block per bucket; counting sort by dst-low-8 in LDS (2-pass,
// no capacity limit). Emits coalesced perm runs AND per-node off[] directly.
// ---------------------------------------------------------------------------
__global__ __launch_bounds__(256) void fine_sort(const int* __restrict__ entries,
                                                 const int* __restrict__ histS,
                                                 int* __restrict__ perm,
                                                 int* __restrict__ off,
                                                 int nbuck, int nch) {
    __shared__ int cnt[256];
    __shared__ int bs[256];
    const int tid = threadIdx.x, b = blockIdx.x;
    const int start = histS[b * NB];
    const int end   = (b + 1 < nbuck) ? histS[(b + 1) * NB] : N_EDGES;

    cnt[tid] = 0;
    __syncthreads();
    for (int i = start + tid; i < end; i += 256)
        atomicAdd(&cnt[entries[i] >> 21], 1);
    __syncthreads();

    int v = cnt[tid];
    bs[tid] = v;
    __syncthreads();
    for (int st = 1; st < 256; st <<= 1) {
        int t = (tid >= st) ? bs[tid - st] : 0;
        __syncthreads();
        bs[tid] += t;
        __syncthreads();
    }
    const int excl = bs[tid] - v;      // exclusive prefix among dlow

    const int c  = b / NBKT;
    const int dh = b % NBKT;
    const int d  = dh * 256 + tid;
    if (d < N_NODES) off[c * N_NODES + d] = start + excl;
    if (b == nbuck - 1 && tid == 0) off[nch * N_NODES] = N_EDGES;

    __syncthreads();
    cnt[tid] = excl;                   // cursor
    __syncthreads();
    for (int i = start + tid; i < end; i += 256) {
        int en = entries[i];
        int p = atomicAdd(&cnt[en >> 21], 1);
        perm[start + p] = en & 0x1FFFFF;   // (src<<4)|rl
    }
}

// ---------------------------------------------------------------------------
// GEMM, m97-style: 128x128 tile, K=128 via global_load_lds(16B), XOR-swizzled
// ---------------------------------------------------------------------------
__global__ __launch_bounds__(256, 2) void gemm_h(const unsigned short* __restrict__ xb,
                                                 const unsigned short* __restrict__ Bt,
                                                 unsigned short* __restrict__ h2,
                                                 int c, int RC) {
    __shared__ unsigned short lA[128 * 128];
    __shared__ unsigned short lB[128 * 128];

    const int mb = blockIdx.x;
    const int rl = blockIdx.y;
    const int r  = c * RC + rl;
    const int tid  = threadIdx.x;
    const int wid  = tid >> 6;
    const int lane = tid & 63;

    const unsigned short* gA = xb + (size_t)mb * 128 * IN_FEAT;
    const unsigned short* gB = Bt + (size_t)r  * 128 * IN_FEAT;

#pragma unroll
    for (int it = 0; it < 8; ++it) {
        int sbase = it * 256 + wid * 64;
        int s = sbase + lane;
        int row = s >> 4;
        int cc = (s & 15) ^ (row & 15);
        __builtin_amdgcn_global_load_lds(
            (const __attribute__((address_space(1))) void*)(gA + row * 128 + cc * 8),
            (__attribute__((address_space(3))) void*)(&lA[sbase * 8]), 16, 0, 0);
    }
#pragma unroll
    for (int it = 0; it < 8; ++it) {
        int sbase = it * 256 + wid * 64;
        int s = sbase + lane;
        int row = s >> 4;
        int cc = (s & 15) ^ (row & 15);
        __builtin_amdgcn_global_load_lds(
            (const __attribute__((address_space(1))) void*)(gB + row * 128 + cc * 8),
            (__attribute__((address_space(3))) void*)(&lB[sbase * 8]), 16, 0, 0);
    }
    __syncthreads();

    const int wm = wid >> 1, wn = wid & 1;
    const int ml = lane & 15, kgrp = lane >> 4;

    v4f acc[4][4];
#pragma unroll
    for (int i = 0; i < 4; ++i)
#pragma unroll
        for (int j = 0; j < 4; ++j)
            acc[i][j] = (v4f){0.f, 0.f, 0.f, 0.f};

#pragma unroll
    for (int kb = 0; kb < 4; ++kb) {
        const int cc = kb * 4 + kgrp;
        short8 af[4], bfr[4];
#pragma unroll
        for (int tm = 0; tm < 4; ++tm) {
            int rA = wm * 64 + tm * 16 + ml;
            af[tm] = *reinterpret_cast<const short8*>(&lA[(rA * 16 + (cc ^ (rA & 15))) * 8]);
        }
#pragma unroll
        for (int tn = 0; tn < 4; ++tn) {
            int rB = wn * 64 + tn * 16 + ml;
            bfr[tn] = *reinterpret_cast<const short8*>(&lB[(rB * 16 + (cc ^ (rB & 15))) * 8]);
        }
#pragma unroll
        for (int tm = 0; tm < 4; ++tm)
#pragma unroll
            for (int tn = 0; tn < 4; ++tn)
                acc[tm][tn] = __builtin_amdgcn_mfma_f32_16x16x32_bf16(af[tm], bfr[tn], acc[tm][tn], 0, 0, 0);
    }

    const int ncols = RC * 128;
    const int row0 = mb * 128 + wm * 64;
    const int col0 = rl * 128 + wn * 64;
#pragma unroll
    for (int tm = 0; tm < 4; ++tm)
#pragma unroll
        for (int rr = 0; rr < 4; ++rr) {
            int row = row0 + tm * 16 + kgrp * 4 + rr;
            size_t rb = (size_t)row * ncols;
#pragma unroll
            for (int tn = 0; tn < 4; ++tn) {
                int col = col0 + tn * 16 + ml;
                h2[rb + col] = f2bf_rne(acc[tm][tn][rr]);
            }
        }
}

// ---------------------------------------------------------------------------
// Gather: one wave per (chunk, node) segment. 16-wide main unroll for MLP
// (~16 scattered 4B reads in flight per lane), then 8/2/1 tails. RC is a
// template param so the h2 row stride is a compile-time shift.
// ---------------------------------------------------------------------------
template <int RCT>
__global__ void gatherT(const int* __restrict__ off, const int* __restrict__ perm,
                        const unsigned short* __restrict__ h2,
                        const float* __restrict__ bias,
                        float* __restrict__ out, int c) {
    const int d = blockIdx.x * 4 + (threadIdx.x >> 6);
    const int lane = threadIdx.x & 63;
    const int kb = c * N_NODES + d;
    const int e0 = off[kb], e1 = off[kb + 1];
    const unsigned short* hb = h2 + lane * 2;   // lane-fixed byte offset
    float2 acc = make_float2(0.f, 0.f);
    int e = e0;
    for (; e + 16 <= e1; e += 16) {
        int p[16];
#pragma unroll
        for (int j = 0; j < 16; ++j) p[j] = perm[e + j];
        ushort2 v[16];
#pragma unroll
        for (int j = 0; j < 16; ++j)
            v[j] = *reinterpret_cast<const ushort2*>(
                hb + ((size_t)(p[j] >> 4) * RCT + (p[j] & 15)) * 128);
#pragma unroll
        for (int j = 0; j < 16; ++j) {
            acc.x += bf2f(v[j].x);
            acc.y += bf2f(v[j].y);
        }
    }
    for (; e + 8 <= e1; e += 8) {
        int p[8];
#pragma unroll
        for (int j = 0; j < 8; ++j) p[j] = perm[e + j];
        ushort2 v[8];
#pragma unroll
        for (int j = 0; j < 8; ++j)
            v[j] = *reinterpret_cast<const ushort2*>(
                hb + ((size_t)(p[j] >> 4) * RCT + (p[j] & 15)) * 128);
#pragma unroll
        for (int j = 0; j < 8; ++j) {
            acc.x += bf2f(v[j].x);
            acc.y += bf2f(v[j].y);
        }
    }
    for (; e + 2 <= e1; e += 2) {
        int p0 = perm[e], p1 = perm[e + 1];
        ushort2 v0 = *reinterpret_cast<const ushort2*>(
            hb + ((size_t)(p0 >> 4) * RCT + (p0 & 15)) * 128);
        ushort2 v1 = *reinterpret_cast<const ushort2*>(
            hb + ((size_t)(p1 >> 4) * RCT + (p1 & 15)) * 128);
        acc.x += bf2f(v0.x) + bf2f(v1.x);
        acc.y += bf2f(v0.y) + bf2f(v1.y);
    }
    for (; e < e1; ++e) {
        int p = perm[e];
        ushort2 v = *reinterpret_cast<const ushort2*>(
            hb + ((size_t)(p >> 4) * RCT + (p & 15)) * 128);
        acc.x += bf2f(v.x);
        acc.y += bf2f(v.y);
    }
    float* po = out + (size_t)d * OUT_FEAT + lane * 2;
    if (c == 0) {
        acc.x += bias[lane * 2];
        acc.y += bias[lane * 2 + 1];
    } else {
        float2 prev = *reinterpret_cast<const float2*>(po);
        acc.x += prev.x;
        acc.y += prev.y;
    }
    *reinterpret_cast<float2*>(po) = acc;
}

static inline size_t align256(size_t a) { return (a + 255) & ~(size_t)255; }

extern "C" void kernel_launch(void* const* d_in, const int* in_sizes, int n_in,
                              void* d_out, int out_size, void* d_ws, size_t ws_size,
                              hipStream_t stream) {
    const float* x      = (const float*)d_in[0];
    const float* weight = (const float*)d_in[1];
    const float* w_comp = (const float*)d_in[2];
    const float* h_bias = (const float*)d_in[3];
    const int*   src    = (const int*)d_in[4];
    const int*   dst    = (const int*)d_in[5];
    const int*   etypes = (const int*)d_in[6];
    float* out = (float*)d_out;

    const size_t per_rel = (size_t)M_PAD * 128 * 2;   // 25,624,576 B

    // RC=16 (single chunk): measured best. RC=4 L3-chunking was tried and
    // regressed (574 vs 552 us): per-pass gather gains < 4x out-accumulation
    // traffic + per-pass fixed overhead. Fallback loop retained for small ws.
    int RC = 16, lg = 4;
    size_t perm_o = 0, off_o = 0, part_o = 0, h2_o = 0;
    for (;;) {
        int nch = NUM_RELS / RC;
        size_t a = 512 * 1024;                                   // Bt
        a = align256(a + per_rel);                               // xb
        perm_o = a; a = align256(a + (size_t)N_EDGES * 4);       // perm
        off_o  = a; a = align256(a + ((size_t)nch * N_NODES + 1) * 4);
        part_o = a; a = align256(a + 512 * 4);                   // scan partials
        h2_o   = a; a += per_rel * (size_t)RC;                   // h2 (>= 25.6MB)
        if (a <= ws_size || RC == 1) break;
        RC >>= 1; lg -= 1;
    }
    const int nch = NUM_RELS / RC;
    const int nbuck = nch * NBKT;
    const int K2 = nbuck * NB;
    const int G2 = (K2 + 4095) / 4096;

    char* w = (char*)d_ws;
    unsigned short* Bt      = (unsigned short*)(w);
    unsigned short* xb      = (unsigned short*)(w + 512 * 1024);
    int*            perm    = (int*)(w + perm_o);
    int*            off     = (int*)(w + off_o);
    int*            partial = (int*)(w + part_o);
    unsigned short* h2      = (unsigned short*)(w + h2_o);
    int*            entries = (int*)(w + h2_o);                  // alias h2[0..12.8MB)
    int*            histG   = (int*)(w + h2_o + 13 * 1024 * 1024); // alias h2[13MB..)

    conv_x<<<12512, 256, 0, stream>>>(x, xb);
    build_w<<<1024, 256, 0, stream>>>(weight, w_comp, Bt);

    coarse_hist<<<NB, 512, nbuck * 4, stream>>>(dst, etypes, histG, lg, nbuck);
    scan_part<<<G2, 256, 0, stream>>>(histG, partial, K2);
    scan_mid<<<1, 512, 0, stream>>>(partial, G2);
    scan_final<<<G2, 256, 0, stream>>>(histG, partial, K2);
    coarse_place<<<NB, 512, nbuck * 4, stream>>>(src, dst, etypes, histG, entries,
                                                 lg, RC - 1, nbuck);
    fine_sort<<<nbuck, 256, 0, stream>>>(entries, histG, perm, off, nbuck, nch);

    for (int c = 0; c < nch; ++c) {
        gemm_h<<<dim3(782, RC), 256, 0, stream>>>(xb, Bt, h2, c, RC);
        switch (RC) {
            case 16: gatherT<16><<<25000, 256, 0, stream>>>(off, perm, h2, h_bias, out, c); break;
            case 8:  gatherT<8> <<<25000, 256, 0, stream>>>(off, perm, h2, h_bias, out, c); break;
            case 4:  gatherT<4> <<<25000, 256, 0, stream>>>(off, perm, h2, h_bias, out, c); break;
            case 2:  gatherT<2> <<<25000, 256, 0, stream>>>(off, perm, h2, h_bias, out, c); break;
            default: gatherT<1> <<<25000, 256, 0, stream>>>(off, perm, h2, h_bias, out, c); break;
        }
    }
}

// Round 6
// 424.574 us; speedup vs baseline: 1.3513x; 1.2735x over previous
//
#include <hip/hip_runtime.h>
#include <hip/hip_bf16.h>
#include <stdint.h>

#define N_NODES   100000
#define N_EDGES   3200000
#define IN_FEAT   128
#define OUT_FEAT  128
#define NUM_RELS  16
#define NUM_BASES 8
#define M_PAD     100096      // 782 * 128
#define NBKT      391         // coarse buckets = ceil(100000/256)
#define NB        512         // blocks in coarse hist/place (must match both)

using short8 = __attribute__((ext_vector_type(8))) short;
using v4f    = __attribute__((ext_vector_type(4))) float;

__device__ inline unsigned short f2bf_rne(float f) {
    __hip_bfloat16 h = __float2bfloat16(f);
    return *reinterpret_cast<unsigned short*>(&h);
}
__device__ inline float bf2f(unsigned short u) {
    union { uint32_t i; float f; } x;
    x.i = ((uint32_t)u) << 16;
    return x.f;
}

// ---------------------------------------------------------------------------
// x fp32 -> bf16, zero-padded to M_PAD rows
// ---------------------------------------------------------------------------
__global__ void conv_x(const float* __restrict__ x, unsigned short* __restrict__ xb) {
    int id = blockIdx.x * 256 + threadIdx.x;
    int base = id * 4;
    ushort4 o;
    if (base < N_NODES * IN_FEAT) {
        const float4 v = reinterpret_cast<const float4*>(x)[id];
        o.x = f2bf_rne(v.x); o.y = f2bf_rne(v.y);
        o.z = f2bf_rne(v.z); o.w = f2bf_rne(v.w);
    } else {
        o.x = o.y = o.z = o.w = 0;
    }
    reinterpret_cast<ushort4*>(xb)[id] = o;
}

// ---------------------------------------------------------------------------
// Ut[o][b*128+i] = bf16(weight[b][i][o]) -- basis matrices, transposed so
// both zgemm operands are row-major-over-K. 128 x 1024 bf16 = 256 KB.
// ---------------------------------------------------------------------------
__global__ void build_ut(const float* __restrict__ weight,
                         unsigned short* __restrict__ Ut) {
    int id = blockIdx.x * 256 + threadIdx.x;   // 512 blocks * 256 = 131072
    int o  = id >> 10;
    int kk = id & 1023;
    int b  = kk >> 7;
    int i  = kk & 127;
    Ut[id] = f2bf_rne(weight[(b * IN_FEAT + i) * OUT_FEAT + o]);
}

// ---------------------------------------------------------------------------
// Sort by dst. Coarse bucket b = dst>>8.
// Phase 1: per-block LDS histogram -> histG[b*NB + nb]  (no global atomics)
// ---------------------------------------------------------------------------
__global__ __launch_bounds__(512) void coarse_hist(const int* __restrict__ dst,
                                                   int* __restrict__ histG,
                                                   int nbuck) {
    extern __shared__ int lh[];
    for (int i = threadIdx.x; i < nbuck; i += 512) lh[i] = 0;
    __syncthreads();
    const int NG = N_EDGES / 4;
    const int stride = NB * 512;
    for (int g = blockIdx.x * 512 + threadIdx.x; g < NG; g += stride) {
        const int4 d4 = reinterpret_cast<const int4*>(dst)[g];
        atomicAdd(&lh[d4.x >> 8], 1);
        atomicAdd(&lh[d4.y >> 8], 1);
        atomicAdd(&lh[d4.z >> 8], 1);
        atomicAdd(&lh[d4.w >> 8], 1);
    }
    __syncthreads();
    for (int i = threadIdx.x; i < nbuck; i += 512)
        histG[i * NB + blockIdx.x] = lh[i];
}

// ---------------------------------------------------------------------------
// 2-level in-place exclusive scan of data[0..K): part -> mid -> final
// ---------------------------------------------------------------------------
__global__ void scan_part(const int* __restrict__ data, int* __restrict__ partial, int K) {
    __shared__ int sh[256];
    const int tid = threadIdx.x, b = blockIdx.x;
    const int i0 = b * 4096 + tid * 16;
    int s = 0;
#pragma unroll
    for (int k = 0; k < 16; ++k) { int i = i0 + k; if (i < K) s += data[i]; }
    sh[tid] = s;
    __syncthreads();
    for (int st = 128; st > 0; st >>= 1) {
        if (tid < st) sh[tid] += sh[tid + st];
        __syncthreads();
    }
    if (tid == 0) partial[b] = sh[0];
}

__global__ __launch_bounds__(512) void scan_mid(int* __restrict__ partial, int G) {
    __shared__ int sh[512];
    const int tid = threadIdx.x;
    int v = (tid < G) ? partial[tid] : 0;
    sh[tid] = v;
    __syncthreads();
    for (int st = 1; st < 512; st <<= 1) {
        int t = (tid >= st) ? sh[tid - st] : 0;
        __syncthreads();
        sh[tid] += t;
        __syncthreads();
    }
    if (tid < G) partial[tid] = sh[tid] - v;        // exclusive
}

// in-place: each element read before overwrite by the same thread
__global__ void scan_final(int* __restrict__ data, const int* __restrict__ partial, int K) {
    __shared__ int sh[256];
    const int tid = threadIdx.x, b = blockIdx.x;
    const int i0 = b * 4096 + tid * 16;
    int s = 0;
#pragma unroll
    for (int k = 0; k < 16; ++k) { int i = i0 + k; if (i < K) s += data[i]; }
    sh[tid] = s;
    __syncthreads();
    for (int st = 1; st < 256; st <<= 1) {
        int t = (tid >= st) ? sh[tid - st] : 0;
        __syncthreads();
        sh[tid] += t;
        __syncthreads();
    }
    int run = partial[b] + sh[tid] - s;
#pragma unroll
    for (int k = 0; k < 16; ++k) {
        int i = i0 + k;
        if (i < K) {
            int c = data[i];
            data[i] = run;
            run += c;
        }
    }
}

// ---------------------------------------------------------------------------
// Phase 2: place edges into bucket-contiguous regions using exact reserved
// ranges (histS = scanned histG). LDS cursors only.
// entry = (dst&255)<<21 | src<<4 | rl   (29 bits)
// ---------------------------------------------------------------------------
__global__ __launch_bounds__(512) void coarse_place(const int* __restrict__ src,
                                                    const int* __restrict__ dst,
                                                    const int* __restrict__ et,
                                                    const int* __restrict__ histS,
                                                    int* __restrict__ entries,
                                                    int nbuck) {
    extern __shared__ int cur[];
    for (int i = threadIdx.x; i < nbuck; i += 512)
        cur[i] = histS[i * NB + blockIdx.x];
    __syncthreads();
    const int NG = N_EDGES / 4;
    const int stride = NB * 512;
    for (int g = blockIdx.x * 512 + threadIdx.x; g < NG; g += stride) {
        const int4 s4 = reinterpret_cast<const int4*>(src)[g];
        const int4 d4 = reinterpret_cast<const int4*>(dst)[g];
        const int4 t4 = reinterpret_cast<const int4*>(et)[g];
        int p0 = atomicAdd(&cur[d4.x >> 8], 1);
        int p1 = atomicAdd(&cur[d4.y >> 8], 1);
        int p2 = atomicAdd(&cur[d4.z >> 8], 1);
        int p3 = atomicAdd(&cur[d4.w >> 8], 1);
        entries[p0] = ((d4.x & 255) << 21) | (s4.x << 4) | (t4.x & 15);
        entries[p1] = ((d4.y & 255) << 21) | (s4.y << 4) | (t4.y & 15);
        entries[p2] = ((d4.z & 255) << 21) | (s4.z << 4) | (t4.z & 15);
        entries[p3] = ((d4.w & 255) << 21) | (s4.w << 4) | (t4.w & 15);
    }
}

// ---------------------------------------------------------------------------
// Phase 3: one block per bucket; counting sort by dst-low-8 in LDS (2-pass,
// no capacity limit). Emits coalesced perm runs AND per-node off[] directly.
// ---------------------------------------------------------------------------
__global__ __launch_bounds__(256) void fine_sort(const int* __restrict__ entries,
                                                 const int* __restrict__ histS,
                                                 int* __restrict__ perm,
                                                 int* __restrict__ off,
                                                 int nbuck) {
    __shared__ int cnt[256];
    __shared__ int bs[256];
    const int tid = threadIdx.x, b = blockIdx.x;
    const int start = histS[b * NB];
    const int end   = (b + 1 < nbuck) ? histS[(b + 1) * NB] : N_EDGES;

    cnt[tid] = 0;
    __syncthreads();
    for (int i = start + tid; i < end; i += 256)
        atomicAdd(&cnt[entries[i] >> 21], 1);
    __syncthreads();

    int v = cnt[tid];
    bs[tid] = v;
    __syncthreads();
    for (int st = 1; st < 256; st <<= 1) {
        int t = (tid >= st) ? bs[tid - st] : 0;
        __syncthreads();
        bs[tid] += t;
        __syncthreads();
    }
    const int excl = bs[tid] - v;      // exclusive prefix among dlow

    const int d = b * 256 + tid;
    if (d < N_NODES) off[d] = start + excl;
    if (b == nbuck - 1 && tid == 0) off[N_NODES] = N_EDGES;

    __syncthreads();
    cnt[tid] = excl;                   // cursor
    __syncthreads();
    for (int i = start + tid; i < end; i += 256) {
        int en = entries[i];
        int p = atomicAdd(&cnt[en >> 21], 1);
        perm[start + p] = en & 0x1FFFFF;   // (src<<4)|rl
    }
}

// ---------------------------------------------------------------------------
// Basis-space aggregation: z[d, b, :] = sum_{edges into d} w_comp[rl,b]*x[src].
// One wave per node. Per edge: 256B read of L3-resident xb + 16 FMA/lane into
// 8 float2 accumulators. Replaces the h2 gather (410 MB random target).
// ---------------------------------------------------------------------------
__global__ void gather_z(const int* __restrict__ off, const int* __restrict__ perm,
                         const unsigned short* __restrict__ xb,
                         const float* __restrict__ w_comp,
                         unsigned short* __restrict__ zb) {
    __shared__ float csh[NUM_RELS * NUM_BASES];
    if (threadIdx.x < NUM_RELS * NUM_BASES) csh[threadIdx.x] = w_comp[threadIdx.x];
    __syncthreads();
    const int d = blockIdx.x * 4 + (threadIdx.x >> 6);
    const int lane = threadIdx.x & 63;
    float2 z[8];
#pragma unroll
    for (int b = 0; b < 8; ++b) z[b] = make_float2(0.f, 0.f);
    if (d < N_NODES) {
        const int e0 = off[d], e1 = off[d + 1];
        const unsigned short* xl = xb + lane * 2;
        int e = e0;
        for (; e + 8 <= e1; e += 8) {
            int p[8];
#pragma unroll
            for (int j = 0; j < 8; ++j) p[j] = perm[e + j];
            ushort2 v[8];
#pragma unroll
            for (int j = 0; j < 8; ++j)
                v[j] = *reinterpret_cast<const ushort2*>(xl + (size_t)(p[j] >> 4) * 128);
#pragma unroll
            for (int j = 0; j < 8; ++j) {
                const float4 cA = *reinterpret_cast<const float4*>(&csh[(p[j] & 15) * 8]);
                const float4 cB = *reinterpret_cast<const float4*>(&csh[(p[j] & 15) * 8 + 4]);
                const float xlo = bf2f(v[j].x), xhi = bf2f(v[j].y);
                z[0].x += cA.x * xlo; z[0].y += cA.x * xhi;
                z[1].x += cA.y * xlo; z[1].y += cA.y * xhi;
                z[2].x += cA.z * xlo; z[2].y += cA.z * xhi;
                z[3].x += cA.w * xlo; z[3].y += cA.w * xhi;
                z[4].x += cB.x * xlo; z[4].y += cB.x * xhi;
                z[5].x += cB.y * xlo; z[5].y += cB.y * xhi;
                z[6].x += cB.z * xlo; z[6].y += cB.z * xhi;
                z[7].x += cB.w * xlo; z[7].y += cB.w * xhi;
            }
        }
        for (; e < e1; ++e) {
            int p = perm[e];
            ushort2 v = *reinterpret_cast<const ushort2*>(xl + (size_t)(p >> 4) * 128);
            const float4 cA = *reinterpret_cast<const float4*>(&csh[(p & 15) * 8]);
            const float4 cB = *reinterpret_cast<const float4*>(&csh[(p & 15) * 8 + 4]);
            const float xlo = bf2f(v.x), xhi = bf2f(v.y);
            z[0].x += cA.x * xlo; z[0].y += cA.x * xhi;
            z[1].x += cA.y * xlo; z[1].y += cA.y * xhi;
            z[2].x += cA.z * xlo; z[2].y += cA.z * xhi;
            z[3].x += cA.w * xlo; z[3].y += cA.w * xhi;
            z[4].x += cB.x * xlo; z[4].y += cB.x * xhi;
            z[5].x += cB.y * xlo; z[5].y += cB.y * xhi;
            z[6].x += cB.z * xlo; z[6].y += cB.z * xhi;
            z[7].x += cB.w * xlo; z[7].y += cB.w * xhi;
        }
    }
    // store z row (pad rows d in [N_NODES, M_PAD) get zeros so zgemm reads clean)
    unsigned short* zr = zb + (size_t)d * 1024 + lane * 2;
#pragma unroll
    for (int b = 0; b < 8; ++b) {
        ushort2 o;
        o.x = f2bf_rne(z[b].x);
        o.y = f2bf_rne(z[b].y);
        *reinterpret_cast<ushort2*>(zr + b * 128) = o;
    }
}

// ---------------------------------------------------------------------------
// out = z (M_PAD x 1024) * Ut^T (128 x 1024) + bias.  m97-style 128x128 tile
// with 8-step K-loop via global_load_lds(16B), XOR-swizzled LDS.
// ---------------------------------------------------------------------------
__global__ __launch_bounds__(256, 2) void zgemm(const unsigned short* __restrict__ zb,
                                                const unsigned short* __restrict__ Ut,
                                                const float* __restrict__ bias,
                                                float* __restrict__ out) {
    __shared__ unsigned short lA[128 * 128];
    __shared__ unsigned short lB[128 * 128];

    const int mb = blockIdx.x;
    const int tid  = threadIdx.x;
    const int wid  = tid >> 6;
    const int lane = tid & 63;
    const int wm = wid >> 1, wn = wid & 1;
    const int ml = lane & 15, kgrp = lane >> 4;

    const unsigned short* gA = zb + (size_t)mb * 128 * 1024;

    v4f acc[4][4];
#pragma unroll
    for (int i = 0; i < 4; ++i)
#pragma unroll
        for (int j = 0; j < 4; ++j)
            acc[i][j] = (v4f){0.f, 0.f, 0.f, 0.f};

    for (int kt = 0; kt < 8; ++kt) {
#pragma unroll
        for (int it = 0; it < 8; ++it) {
            int sbase = it * 256 + wid * 64;
            int s = sbase + lane;
            int row = s >> 4;
            int cc = (s & 15) ^ (row & 15);
            __builtin_amdgcn_global_load_lds(
                (const __attribute__((address_space(1))) void*)(gA + (size_t)row * 1024 + kt * 128 + cc * 8),
                (__attribute__((address_space(3))) void*)(&lA[sbase * 8]), 16, 0, 0);
            __builtin_amdgcn_global_load_lds(
                (const __attribute__((address_space(1))) void*)(Ut + (size_t)row * 1024 + kt * 128 + cc * 8),
                (__attribute__((address_space(3))) void*)(&lB[sbase * 8]), 16, 0, 0);
        }
        __syncthreads();

#pragma unroll
        for (int kb = 0; kb < 4; ++kb) {
            const int cc = kb * 4 + kgrp;
            short8 af[4], bfr[4];
#pragma unroll
            for (int tm = 0; tm < 4; ++tm) {
                int rA = wm * 64 + tm * 16 + ml;
                af[tm] = *reinterpret_cast<const short8*>(&lA[(rA * 16 + (cc ^ (rA & 15))) * 8]);
            }
#pragma unroll
            for (int tn = 0; tn < 4; ++tn) {
                int rB = wn * 64 + tn * 16 + ml;
                bfr[tn] = *reinterpret_cast<const short8*>(&lB[(rB * 16 + (cc ^ (rB & 15))) * 8]);
            }
#pragma unroll
            for (int tm = 0; tm < 4; ++tm)
#pragma unroll
                for (int tn = 0; tn < 4; ++tn)
                    acc[tm][tn] = __builtin_amdgcn_mfma_f32_16x16x32_bf16(af[tm], bfr[tn], acc[tm][tn], 0, 0, 0);
        }
        __syncthreads();
    }

    const int row0 = mb * 128 + wm * 64;
    const int col0 = wn * 64;
#pragma unroll
    for (int tm = 0; tm < 4; ++tm)
#pragma unroll
        for (int rr = 0; rr < 4; ++rr) {
            int row = row0 + tm * 16 + kgrp * 4 + rr;
            if (row < N_NODES) {
                size_t rb = (size_t)row * OUT_FEAT;
#pragma unroll
                for (int tn = 0; tn < 4; ++tn) {
                    int col = col0 + tn * 16 + ml;
                    out[rb + col] = acc[tm][tn][rr] + bias[col];
                }
            }
        }
}

static inline size_t align256(size_t a) { return (a + 255) & ~(size_t)255; }

extern "C" void kernel_launch(void* const* d_in, const int* in_sizes, int n_in,
                              void* d_out, int out_size, void* d_ws, size_t ws_size,
                              hipStream_t stream) {
    const float* x      = (const float*)d_in[0];
    const float* weight = (const float*)d_in[1];
    const float* w_comp = (const float*)d_in[2];
    const float* h_bias = (const float*)d_in[3];
    const int*   src    = (const int*)d_in[4];
    const int*   dst    = (const int*)d_in[5];
    const int*   etypes = (const int*)d_in[6];
    float* out = (float*)d_out;

    const int nbuck = NBKT;
    const int K2 = nbuck * NB;                 // 200192
    const int G2 = (K2 + 4095) / 4096;         // 49

    // Workspace layout (total ~244 MB):
    //   Ut 512KB | xb 25.6MB | perm 12.8MB | off 0.4MB | partial | zb 205MB
    // entries (12.8MB) and histG (0.8MB) alias zb -- dead before gather_z.
    size_t a = 512 * 1024;                                    // Ut
    size_t xb_o = a;   a = align256(a + (size_t)M_PAD * 128 * 2);
    size_t perm_o = a; a = align256(a + (size_t)N_EDGES * 4);
    size_t off_o = a;  a = align256(a + ((size_t)N_NODES + 1) * 4);
    size_t part_o = a; a = align256(a + 512 * 4);
    size_t zb_o = a;   // zb: M_PAD * 1024 * 2 = 205 MB

    char* w = (char*)d_ws;
    unsigned short* Ut      = (unsigned short*)(w);
    unsigned short* xb      = (unsigned short*)(w + xb_o);
    int*            perm    = (int*)(w + perm_o);
    int*            off     = (int*)(w + off_o);
    int*            partial = (int*)(w + part_o);
    unsigned short* zb      = (unsigned short*)(w + zb_o);
    int*            entries = (int*)(w + zb_o);                    // alias zb
    int*            histG   = (int*)(w + zb_o + 13 * 1024 * 1024); // alias zb+13MB

    conv_x<<<12512, 256, 0, stream>>>(x, xb);
    build_ut<<<512, 256, 0, stream>>>(weight, Ut);

    coarse_hist<<<NB, 512, nbuck * 4, stream>>>(dst, histG, nbuck);
    scan_part<<<G2, 256, 0, stream>>>(histG, partial, K2);
    scan_mid<<<1, 512, 0, stream>>>(partial, G2);
    scan_final<<<G2, 256, 0, stream>>>(histG, partial, K2);
    coarse_place<<<NB, 512, nbuck * 4, stream>>>(src, dst, etypes, histG, entries, nbuck);
    fine_sort<<<nbuck, 256, 0, stream>>>(entries, histG, perm, off, nbuck);

    gather_z<<<25024, 256, 0, stream>>>(off, perm, xb, w_comp, zb);
    zgemm<<<782, 256, 0, stream>>>(zb, Ut, h_bias, out);
}

// Round 7
// 415.283 us; speedup vs baseline: 1.3815x; 1.0224x over previous
//
#include <hip/hip_runtime.h>
#include <hip/hip_bf16.h>
#include <stdint.h>

#define N_NODES   100000
#define N_EDGES   3200000
#define IN_FEAT   128
#define OUT_FEAT  128
#define NUM_RELS  16
#define NUM_BASES 8
#define M_PAD     100096      // 782 * 128
#define NBKT      391         // coarse buckets = ceil(100000/256)
#define NB        512         // blocks in coarse hist/place (must match both)

using short8 = __attribute__((ext_vector_type(8))) short;
using v4f    = __attribute__((ext_vector_type(4))) float;

__device__ inline unsigned short f2bf_rne(float f) {
    __hip_bfloat16 h = __float2bfloat16(f);
    return *reinterpret_cast<unsigned short*>(&h);
}
__device__ inline float bf2f(unsigned short u) {
    union { uint32_t i; float f; } x;
    x.i = ((uint32_t)u) << 16;
    return x.f;
}

// ---------------------------------------------------------------------------
// x fp32 -> bf16, zero-padded to M_PAD rows
// ---------------------------------------------------------------------------
__global__ void conv_x(const float* __restrict__ x, unsigned short* __restrict__ xb) {
    int id = blockIdx.x * 256 + threadIdx.x;
    int base = id * 4;
    ushort4 o;
    if (base < N_NODES * IN_FEAT) {
        const float4 v = reinterpret_cast<const float4*>(x)[id];
        o.x = f2bf_rne(v.x); o.y = f2bf_rne(v.y);
        o.z = f2bf_rne(v.z); o.w = f2bf_rne(v.w);
    } else {
        o.x = o.y = o.z = o.w = 0;
    }
    reinterpret_cast<ushort4*>(xb)[id] = o;
}

// ---------------------------------------------------------------------------
// Ut[o][b*128+i] = bf16(weight[b][i][o]) -- basis matrices, transposed so
// both zgemm operands are row-major-over-K. 128 x 1024 bf16 = 256 KB.
// ---------------------------------------------------------------------------
__global__ void build_ut(const float* __restrict__ weight,
                         unsigned short* __restrict__ Ut) {
    int id = blockIdx.x * 256 + threadIdx.x;   // 512 blocks * 256 = 131072
    int o  = id >> 10;
    int kk = id & 1023;
    int b  = kk >> 7;
    int i  = kk & 127;
    Ut[id] = f2bf_rne(weight[(b * IN_FEAT + i) * OUT_FEAT + o]);
}

// ---------------------------------------------------------------------------
// Sort by dst. Coarse bucket b = dst>>8.
// Phase 1: per-block LDS histogram -> histG[b*NB + nb]  (no global atomics)
// ---------------------------------------------------------------------------
__global__ __launch_bounds__(512) void coarse_hist(const int* __restrict__ dst,
                                                   int* __restrict__ histG,
                                                   int nbuck) {
    extern __shared__ int lh[];
    for (int i = threadIdx.x; i < nbuck; i += 512) lh[i] = 0;
    __syncthreads();
    const int NG = N_EDGES / 4;
    const int stride = NB * 512;
    for (int g = blockIdx.x * 512 + threadIdx.x; g < NG; g += stride) {
        const int4 d4 = reinterpret_cast<const int4*>(dst)[g];
        atomicAdd(&lh[d4.x >> 8], 1);
        atomicAdd(&lh[d4.y >> 8], 1);
        atomicAdd(&lh[d4.z >> 8], 1);
        atomicAdd(&lh[d4.w >> 8], 1);
    }
    __syncthreads();
    for (int i = threadIdx.x; i < nbuck; i += 512)
        histG[i * NB + blockIdx.x] = lh[i];
}

// ---------------------------------------------------------------------------
// 2-level in-place exclusive scan of data[0..K): part -> mid -> final
// ---------------------------------------------------------------------------
__global__ void scan_part(const int* __restrict__ data, int* __restrict__ partial, int K) {
    __shared__ int sh[256];
    const int tid = threadIdx.x, b = blockIdx.x;
    const int i0 = b * 4096 + tid * 16;
    int s = 0;
#pragma unroll
    for (int k = 0; k < 16; ++k) { int i = i0 + k; if (i < K) s += data[i]; }
    sh[tid] = s;
    __syncthreads();
    for (int st = 128; st > 0; st >>= 1) {
        if (tid < st) sh[tid] += sh[tid + st];
        __syncthreads();
    }
    if (tid == 0) partial[b] = sh[0];
}

__global__ __launch_bounds__(512) void scan_mid(int* __restrict__ partial, int G) {
    __shared__ int sh[512];
    const int tid = threadIdx.x;
    int v = (tid < G) ? partial[tid] : 0;
    sh[tid] = v;
    __syncthreads();
    for (int st = 1; st < 512; st <<= 1) {
        int t = (tid >= st) ? sh[tid - st] : 0;
        __syncthreads();
        sh[tid] += t;
        __syncthreads();
    }
    if (tid < G) partial[tid] = sh[tid] - v;        // exclusive
}

// in-place: each element read before overwrite by the same thread
__global__ void scan_final(int* __restrict__ data, const int* __restrict__ partial, int K) {
    __shared__ int sh[256];
    const int tid = threadIdx.x, b = blockIdx.x;
    const int i0 = b * 4096 + tid * 16;
    int s = 0;
#pragma unroll
    for (int k = 0; k < 16; ++k) { int i = i0 + k; if (i < K) s += data[i]; }
    sh[tid] = s;
    __syncthreads();
    for (int st = 1; st < 256; st <<= 1) {
        int t = (tid >= st) ? sh[tid - st] : 0;
        __syncthreads();
        sh[tid] += t;
        __syncthreads();
    }
    int run = partial[b] + sh[tid] - s;
#pragma unroll
    for (int k = 0; k < 16; ++k) {
        int i = i0 + k;
        if (i < K) {
            int c = data[i];
            data[i] = run;
            run += c;
        }
    }
}

// ---------------------------------------------------------------------------
// Phase 2: place edges into bucket-contiguous regions using exact reserved
// ranges (histS = scanned histG). LDS cursors only.
// entry = (dst&255)<<21 | rl<<17 | src   (29 bits; src < 2^17)
// ---------------------------------------------------------------------------
__global__ __launch_bounds__(512) void coarse_place(const int* __restrict__ src,
                                                    const int* __restrict__ dst,
                                                    const int* __restrict__ et,
                                                    const int* __restrict__ histS,
                                                    int* __restrict__ entries,
                                                    int nbuck) {
    extern __shared__ int cur[];
    for (int i = threadIdx.x; i < nbuck; i += 512)
        cur[i] = histS[i * NB + blockIdx.x];
    __syncthreads();
    const int NG = N_EDGES / 4;
    const int stride = NB * 512;
    for (int g = blockIdx.x * 512 + threadIdx.x; g < NG; g += stride) {
        const int4 s4 = reinterpret_cast<const int4*>(src)[g];
        const int4 d4 = reinterpret_cast<const int4*>(dst)[g];
        const int4 t4 = reinterpret_cast<const int4*>(et)[g];
        int p0 = atomicAdd(&cur[d4.x >> 8], 1);
        int p1 = atomicAdd(&cur[d4.y >> 8], 1);
        int p2 = atomicAdd(&cur[d4.z >> 8], 1);
        int p3 = atomicAdd(&cur[d4.w >> 8], 1);
        entries[p0] = ((d4.x & 255) << 21) | ((t4.x & 15) << 17) | s4.x;
        entries[p1] = ((d4.y & 255) << 21) | ((t4.y & 15) << 17) | s4.y;
        entries[p2] = ((d4.z & 255) << 21) | ((t4.z & 15) << 17) | s4.z;
        entries[p3] = ((d4.w & 255) << 21) | ((t4.w & 15) << 17) | s4.w;
    }
}

// ---------------------------------------------------------------------------
// Phase 3: one block per bucket; counting sort by 12-bit key (dlow<<4 | rl)
// in LDS (2-pass). Edge lists become rel-contiguous per node, enabling the
// run-flush gather. Thread tid owns exactly dlow==tid (16 consecutive keys).
// perm entry = rl<<17 | src (21 bits).
// ---------------------------------------------------------------------------
__global__ __launch_bounds__(256) void fine_sort(const int* __restrict__ entries,
                                                 const int* __restrict__ histS,
                                                 int* __restrict__ perm,
                                                 int* __restrict__ off,
                                                 int nbuck) {
    __shared__ int cnt[4096];
    __shared__ int bs[256];
    const int tid = threadIdx.x, b = blockIdx.x;
    const int start = histS[b * NB];
    const int end   = (b + 1 < nbuck) ? histS[(b + 1) * NB] : N_EDGES;

#pragma unroll
    for (int k = 0; k < 16; ++k) cnt[tid * 16 + k] = 0;
    __syncthreads();
    for (int i = start + tid; i < end; i += 256)
        atomicAdd(&cnt[entries[i] >> 17], 1);
    __syncthreads();

    int c[16];
    int tsum = 0;
#pragma unroll
    for (int k = 0; k < 16; ++k) { c[k] = cnt[tid * 16 + k]; tsum += c[k]; }
    bs[tid] = tsum;
    __syncthreads();
    for (int st = 1; st < 256; st <<= 1) {
        int t = (tid >= st) ? bs[tid - st] : 0;
        __syncthreads();
        bs[tid] += t;
        __syncthreads();
    }
    const int excl = bs[tid] - tsum;   // exclusive prefix of this dlow group

    const int d = b * 256 + tid;
    if (d < N_NODES) off[d] = start + excl;
    if (b == nbuck - 1 && tid == 0) off[N_NODES] = N_EDGES;

    int run = excl;
#pragma unroll
    for (int k = 0; k < 16; ++k) { cnt[tid * 16 + k] = run; run += c[k]; }
    __syncthreads();
    for (int i = start + tid; i < end; i += 256) {
        int en = entries[i];
        int p = atomicAdd(&cnt[en >> 17], 1);
        perm[start + p] = en & 0x1FFFFF;   // rl<<17 | src
    }
}

// ---------------------------------------------------------------------------
// Basis-space aggregation with rel-run grouping: edges per node are sorted by
// rel, so we keep a plain running sum srun (2 adds/edge) and expand into the
// 8 basis accumulators (16 FMA) only when rel changes (wave-uniform branch,
// ~14 runs per 32-edge node). zb stores are NON-TEMPORAL so the 205 MB write
// stream does not evict the L3-resident xb (round-6 FETCH was 360 MB: zb
// write-allocate thrashed xb out of L3).
// ---------------------------------------------------------------------------
__global__ void gather_z(const int* __restrict__ off, const int* __restrict__ perm,
                         const unsigned short* __restrict__ xb,
                         const float* __restrict__ w_comp,
                         unsigned short* __restrict__ zb) {
    __shared__ float csh[NUM_RELS * NUM_BASES];
    if (threadIdx.x < NUM_RELS * NUM_BASES) csh[threadIdx.x] = w_comp[threadIdx.x];
    __syncthreads();
    const int d = blockIdx.x * 4 + (threadIdx.x >> 6);
    const int lane = threadIdx.x & 63;
    float2 z[8];
#pragma unroll
    for (int b = 0; b < 8; ++b) z[b] = make_float2(0.f, 0.f);

    if (d < N_NODES) {
        const int e0 = off[d], e1 = off[d + 1];
        const unsigned short* xl = xb + lane * 2;
        int cur = -1;
        float2 srun = make_float2(0.f, 0.f);

        auto flush = [&]() {
            const float4 cA = *reinterpret_cast<const float4*>(&csh[cur * 8]);
            const float4 cB = *reinterpret_cast<const float4*>(&csh[cur * 8 + 4]);
            z[0].x += cA.x * srun.x; z[0].y += cA.x * srun.y;
            z[1].x += cA.y * srun.x; z[1].y += cA.y * srun.y;
            z[2].x += cA.z * srun.x; z[2].y += cA.z * srun.y;
            z[3].x += cA.w * srun.x; z[3].y += cA.w * srun.y;
            z[4].x += cB.x * srun.x; z[4].y += cB.x * srun.y;
            z[5].x += cB.y * srun.x; z[5].y += cB.y * srun.y;
            z[6].x += cB.z * srun.x; z[6].y += cB.z * srun.y;
            z[7].x += cB.w * srun.x; z[7].y += cB.w * srun.y;
        };
        auto step = [&](int p, ushort2 v) {
            int rl = p >> 17;
            if (rl != cur) {               // wave-uniform (all lanes same p)
                flush();
                cur = rl;
                srun = make_float2(0.f, 0.f);
            }
            srun.x += bf2f(v.x);
            srun.y += bf2f(v.y);
        };

        if (e0 < e1) {
            cur = perm[e0] >> 17;          // first run: no leading flush
            int e = e0;
            for (; e + 8 <= e1; e += 8) {
                int p[8];
#pragma unroll
                for (int j = 0; j < 8; ++j) p[j] = perm[e + j];
                ushort2 v[8];
#pragma unroll
                for (int j = 0; j < 8; ++j)
                    v[j] = *reinterpret_cast<const ushort2*>(
                        xl + (size_t)(p[j] & 0x1FFFF) * 128);
#pragma unroll
                for (int j = 0; j < 8; ++j) step(p[j], v[j]);
            }
            for (; e < e1; ++e) {
                int p = perm[e];
                ushort2 v = *reinterpret_cast<const ushort2*>(
                    xl + (size_t)(p & 0x1FFFF) * 128);
                step(p, v);
            }
            flush();                       // final run
        }
    }

    // store z row (pad rows d in [N_NODES, M_PAD) get zeros so zgemm reads
    // clean). Non-temporal: do not allocate zb lines in L2/L3.
    unsigned short* zr = zb + (size_t)d * 1024 + lane * 2;
#pragma unroll
    for (int b = 0; b < 8; ++b) {
        unsigned int u = (unsigned int)f2bf_rne(z[b].x)
                       | ((unsigned int)f2bf_rne(z[b].y) << 16);
        __builtin_nontemporal_store(u, reinterpret_cast<unsigned int*>(zr + b * 128));
    }
}

// ---------------------------------------------------------------------------
// out = z (M_PAD x 1024) * Ut^T (128 x 1024) + bias.  m97-style 128x128 tile
// with 8-step K-loop via global_load_lds(16B), XOR-swizzled LDS.
// ---------------------------------------------------------------------------
__global__ __launch_bounds__(256, 2) void zgemm(const unsigned short* __restrict__ zb,
                                                const unsigned short* __restrict__ Ut,
                                                const float* __restrict__ bias,
                                                float* __restrict__ out) {
    __shared__ unsigned short lA[128 * 128];
    __shared__ unsigned short lB[128 * 128];

    const int mb = blockIdx.x;
    const int tid  = threadIdx.x;
    const int wid  = tid >> 6;
    const int lane = tid & 63;
    const int wm = wid >> 1, wn = wid & 1;
    const int ml = lane & 15, kgrp = lane >> 4;

    const unsigned short* gA = zb + (size_t)mb * 128 * 1024;

    v4f acc[4][4];
#pragma unroll
    for (int i = 0; i < 4; ++i)
#pragma unroll
        for (int j = 0; j < 4; ++j)
            acc[i][j] = (v4f){0.f, 0.f, 0.f, 0.f};

    for (int kt = 0; kt < 8; ++kt) {
#pragma unroll
        for (int it = 0; it < 8; ++it) {
            int sbase = it * 256 + wid * 64;
            int s = sbase + lane;
            int row = s >> 4;
            int cc = (s & 15) ^ (row & 15);
            __builtin_amdgcn_global_load_lds(
                (const __attribute__((address_space(1))) void*)(gA + (size_t)row * 1024 + kt * 128 + cc * 8),
                (__attribute__((address_space(3))) void*)(&lA[sbase * 8]), 16, 0, 0);
            __builtin_amdgcn_global_load_lds(
                (const __attribute__((address_space(1))) void*)(Ut + (size_t)row * 1024 + kt * 128 + cc * 8),
                (__attribute__((address_space(3))) void*)(&lB[sbase * 8]), 16, 0, 0);
        }
        __syncthreads();

#pragma unroll
        for (int kb = 0; kb < 4; ++kb) {
            const int cc = kb * 4 + kgrp;
            short8 af[4], bfr[4];
#pragma unroll
            for (int tm = 0; tm < 4; ++tm) {
                int rA = wm * 64 + tm * 16 + ml;
                af[tm] = *reinterpret_cast<const short8*>(&lA[(rA * 16 + (cc ^ (rA & 15))) * 8]);
            }
#pragma unroll
            for (int tn = 0; tn < 4; ++tn) {
                int rB = wn * 64 + tn * 16 + ml;
                bfr[tn] = *reinterpret_cast<const short8*>(&lB[(rB * 16 + (cc ^ (rB & 15))) * 8]);
            }
#pragma unroll
            for (int tm = 0; tm < 4; ++tm)
#pragma unroll
                for (int tn = 0; tn < 4; ++tn)
                    acc[tm][tn] = __builtin_amdgcn_mfma_f32_16x16x32_bf16(af[tm], bfr[tn], acc[tm][tn], 0, 0, 0);
        }
        __syncthreads();
    }

    const int row0 = mb * 128 + wm * 64;
    const int col0 = wn * 64;
#pragma unroll
    for (int tm = 0; tm < 4; ++tm)
#pragma unroll
        for (int rr = 0; rr < 4; ++rr) {
            int row = row0 + tm * 16 + kgrp * 4 + rr;
            if (row < N_NODES) {
                size_t rb = (size_t)row * OUT_FEAT;
#pragma unroll
                for (int tn = 0; tn < 4; ++tn) {
                    int col = col0 + tn * 16 + ml;
                    out[rb + col] = acc[tm][tn][rr] + bias[col];
                }
            }
        }
}

static inline size_t align256(size_t a) { return (a + 255) & ~(size_t)255; }

extern "C" void kernel_launch(void* const* d_in, const int* in_sizes, int n_in,
                              void* d_out, int out_size, void* d_ws, size_t ws_size,
                              hipStream_t stream) {
    const float* x      = (const float*)d_in[0];
    const float* weight = (const float*)d_in[1];
    const float* w_comp = (const float*)d_in[2];
    const float* h_bias = (const float*)d_in[3];
    const int*   src    = (const int*)d_in[4];
    const int*   dst    = (const int*)d_in[5];
    const int*   etypes = (const int*)d_in[6];
    float* out = (float*)d_out;

    const int nbuck = NBKT;
    const int K2 = nbuck * NB;                 // 200192
    const int G2 = (K2 + 4095) / 4096;         // 49

    // Workspace layout (total ~244 MB):
    //   Ut 512KB | xb 25.6MB | perm 12.8MB | off 0.4MB | partial | zb 205MB
    // entries (12.8MB) and histG (0.8MB) alias zb -- dead before gather_z.
    size_t a = 512 * 1024;                                    // Ut
    size_t xb_o = a;   a = align256(a + (size_t)M_PAD * 128 * 2);
    size_t perm_o = a; a = align256(a + (size_t)N_EDGES * 4);
    size_t off_o = a;  a = align256(a + ((size_t)N_NODES + 1) * 4);
    size_t part_o = a; a = align256(a + 512 * 4);
    size_t zb_o = a;   // zb: M_PAD * 1024 * 2 = 205 MB

    char* w = (char*)d_ws;
    unsigned short* Ut      = (unsigned short*)(w);
    unsigned short* xb      = (unsigned short*)(w + xb_o);
    int*            perm    = (int*)(w + perm_o);
    int*            off     = (int*)(w + off_o);
    int*            partial = (int*)(w + part_o);
    unsigned short* zb      = (unsigned short*)(w + zb_o);
    int*            entries = (int*)(w + zb_o);                    // alias zb
    int*            histG   = (int*)(w + zb_o + 13 * 1024 * 1024); // alias zb+13MB

    conv_x<<<12512, 256, 0, stream>>>(x, xb);
    build_ut<<<512, 256, 0, stream>>>(weight, Ut);

    coarse_hist<<<NB, 512, nbuck * 4, stream>>>(dst, histG, nbuck);
    scan_part<<<G2, 256, 0, stream>>>(histG, partial, K2);
    scan_mid<<<1, 512, 0, stream>>>(partial, G2);
    scan_final<<<G2, 256, 0, stream>>>(histG, partial, K2);
    coarse_place<<<NB, 512, nbuck * 4, stream>>>(src, dst, etypes, histG, entries, nbuck);
    fine_sort<<<nbuck, 256, 0, stream>>>(entries, histG, perm, off, nbuck);

    gather_z<<<25024, 256, 0, stream>>>(off, perm, xb, w_comp, zb);
    zgemm<<<782, 256, 0, stream>>>(zb, Ut, h_bias, out);
}